// Round 10
// baseline (447.759 us; speedup 1.0000x reference)
//
#include <hip/hip_runtime.h>
#include <hip/hip_bf16.h>

#define NN 768
#define CM 384
#define FACT 2112

typedef __attribute__((ext_vector_type(8))) short bf16x8;
typedef __attribute__((ext_vector_type(4))) short bf16x4;
typedef __attribute__((ext_vector_type(4))) float f32x4;
typedef __attribute__((ext_vector_type(2))) float f32x2;
typedef unsigned int u32;
typedef unsigned short u16;

__device__ __forceinline__ float bflo(u32 u){ union{u32 i; float f;} x; x.i = u << 16; return x.f; }
__device__ __forceinline__ float bfhi(u32 u){ union{u32 i; float f;} x; x.i = u & 0xffff0000u; return x.f; }
__device__ __forceinline__ f32x2 bfp(u32 u){
  union { u32 i[2]; f32x2 v; } x;
  x.i[0] = u << 16; x.i[1] = u & 0xffff0000u;
  return x.v;
}
__device__ __forceinline__ u16 f2b(float f){ __hip_bfloat16 b = __float2bfloat16(f); return *(u16*)&b; }

// ---------------- K1: projections + frame rotation (r9 form) ----------------
__global__ __launch_bounds__(256) void k_proj(
    const float* __restrict__ in1d, const float* __restrict__ rot, const float* __restrict__ trans,
    const float* __restrict__ wq, const float* __restrict__ bq_,
    const float* __restrict__ wkv, const float* __restrict__ bkv,
    const float* __restrict__ wqp, const float* __restrict__ bqp_,
    const float* __restrict__ wkvp, const float* __restrict__ bkvp_,
    float* __restrict__ qpack, u16* __restrict__ kpackb, u16* __restrict__ vpackb)
{
  const int n0 = blockIdx.x * 8;
  const int cq = blockIdx.y;
  const int tid = threadIdx.x;
  __shared__ float x[8][CM];
  __shared__ float rs[8][9], ts[8][3];
  __shared__ float pls[96][24];

  for (int idx = tid; idx < 8*CM/4; idx += 256)
    ((float4*)x)[idx] = ((const float4*)(in1d + (size_t)n0*CM))[idx];
  if (tid < 72) rs[tid/9][tid%9] = rot[n0*9 + tid];
  if (tid < 24) ts[tid/3][tid%3] = trans[n0*3 + tid];
  __syncthreads();

  if (cq < 2) {
    for (int ti = tid; ti < 288; ti += 256) {
      int o = cq*288 + ti;
      const float* wcol; float b; int K;
      if (o < 192) { wcol = wq + o;        K = 192; b = bq_[o]; }
      else         { wcol = wkv + (o-192); K = 384; b = bkv[o-192]; }
      float acc[8];
      #pragma unroll
      for (int r = 0; r < 8; ++r) acc[r] = b;
      for (int c4 = 0; c4 < 96; ++c4) {
        float w0 = wcol[(size_t)(c4*4+0)*K];
        float w1 = wcol[(size_t)(c4*4+1)*K];
        float w2c = wcol[(size_t)(c4*4+2)*K];
        float w3 = wcol[(size_t)(c4*4+3)*K];
        #pragma unroll
        for (int r = 0; r < 8; ++r) {
          float4 xv = *(const float4*)&x[r][c4*4];
          acc[r] = fmaf(xv.x, w0, fmaf(xv.y, w1, fmaf(xv.z, w2c, fmaf(xv.w, w3, acc[r]))));
        }
      }
      if (o < 192) {
        int h = o >> 4, cc = o & 15;
        #pragma unroll
        for (int r = 0; r < 8; ++r)
          qpack[((size_t)(n0+r)*12 + h)*28 + cc] = acc[r];
      } else {
        int o2 = o - 192, h = o2 >> 5, u = o2 & 31;
        #pragma unroll
        for (int r = 0; r < 8; ++r) {
          if (u < 16) kpackb[((size_t)(n0+r)*12 + h)*32 + u] = f2b(acc[r]);
          else        vpackb[((size_t)h*NN + n0 + r)*40 + (u - 16)] = f2b(acc[r]);
        }
      }
    }
  } else {
    for (int ti = tid; ti < 288; ti += 256) {
      int comp = ti / 96, ch_l = ti % 96;
      int ch = (cq-2)*96 + ch_l;
      const float* wcol; float b; int K;
      if (ch < 48) { int col = comp*48 + ch;         wcol = wqp + col;  K = 144; b = bqp_[col]; }
      else         { int col = comp*144 + (ch - 48); wcol = wkvp + col; K = 432; b = bkvp_[col]; }
      float acc[8];
      #pragma unroll
      for (int r = 0; r < 8; ++r) acc[r] = b;
      for (int c4 = 0; c4 < 96; ++c4) {
        float w0 = wcol[(size_t)(c4*4+0)*K];
        float w1 = wcol[(size_t)(c4*4+1)*K];
        float w2c = wcol[(size_t)(c4*4+2)*K];
        float w3 = wcol[(size_t)(c4*4+3)*K];
        #pragma unroll
        for (int r = 0; r < 8; ++r) {
          float4 xv = *(const float4*)&x[r][c4*4];
          acc[r] = fmaf(xv.x, w0, fmaf(xv.y, w1, fmaf(xv.z, w2c, fmaf(xv.w, w3, acc[r]))));
        }
      }
      #pragma unroll
      for (int r = 0; r < 8; ++r) pls[ch_l][comp*8 + r] = acc[r];
    }
    __syncthreads();
    for (int idx = tid; idx < 768; idx += 256) {
      int ch_l = idx >> 3, r = idx & 7;
      int ch = (cq-2)*96 + ch_l;
      int n = n0 + r;
      float l0 = pls[ch_l][r], l1 = pls[ch_l][8 + r], l2 = pls[ch_l][16 + r];
      float g0 = rs[r][0]*l0 + rs[r][1]*l1 + rs[r][2]*l2 + ts[r][0];
      float g1 = rs[r][3]*l0 + rs[r][4]*l1 + rs[r][5]*l2 + ts[r][1];
      float g2 = rs[r][6]*l0 + rs[r][7]*l1 + rs[r][8]*l2 + ts[r][2];
      if (ch < 48) {
        int h = ch >> 2, u = ch & 3;
        float* p = &qpack[((size_t)n*12 + h)*28 + 16 + u*3];
        p[0]=g0; p[1]=g1; p[2]=g2;
      } else {
        int c2 = ch - 48, h = c2 / 12, u = c2 % 12;
        if (u < 4) {
          u16* p = &kpackb[((size_t)n*12 + h)*32 + 16 + u*3];
          p[0]=f2b(g0); p[1]=f2b(g1); p[2]=f2b(g2);
        } else {
          u16* p = &vpackb[((size_t)h*NN + n)*40 + 16 + (u-4)*3];
          p[0]=f2b(g0); p[1]=f2b(g1); p[2]=f2b(g2);
        }
      }
    }
  }
}

// ---------------- K2: bias2d = in2d @ w2d  (barrier-free MFMA GEMM, r8-proven) ----------------
__global__ __launch_bounds__(256) void k_bias2d(
    const float* __restrict__ in2d, const float* __restrict__ w2d, u16* __restrict__ bias2d)
{
  const int lane = threadIdx.x & 63, wave = threadIdx.x >> 6;
  const int hcol = lane & 15, lg4 = lane >> 4;
  bf16x8 wfrag[4];
  #pragma unroll
  for (int kk = 0; kk < 4; ++kk)
    #pragma unroll
    for (int e = 0; e < 8; ++e) {
      int c = kk*32 + lg4*8 + e;
      wfrag[kk][e] = (short)((hcol < 12) ? f2b(w2d[c*12 + hcol]) : (u16)0);
    }
  const int gw = blockIdx.x*4 + wave;
  for (int tile = gw; tile < 36864; tile += 4096) {
    const size_t m0 = (size_t)tile * 16;
    const float* arow = in2d + (m0 + hcol)*128 + lg4*8;
    f32x4 acc = {0.f,0.f,0.f,0.f};
    #pragma unroll
    for (int kk = 0; kk < 4; ++kk) {
      float4 a0 = *(const float4*)(arow + kk*32);
      float4 a1 = *(const float4*)(arow + kk*32 + 4);
      bf16x8 af;
      af[0]=(short)f2b(a0.x); af[1]=(short)f2b(a0.y); af[2]=(short)f2b(a0.z); af[3]=(short)f2b(a0.w);
      af[4]=(short)f2b(a1.x); af[5]=(short)f2b(a1.y); af[6]=(short)f2b(a1.z); af[7]=(short)f2b(a1.w);
      acc = __builtin_amdgcn_mfma_f32_16x16x32_bf16(af, wfrag[kk], acc, 0, 0, 0);
    }
    if (hcol < 12) {
      #pragma unroll
      for (int r = 0; r < 4; ++r)
        bias2d[(m0 + lg4*4 + r)*12 + hcol] = f2b(acc[r]);
    }
  }
}

// ---------------- K3: logits + softmax -> normalized attn bf16 [i][h][j] (r8-proven) ----------------
__global__ __launch_bounds__(256) void k_attn(
    const float* __restrict__ mask, const float* __restrict__ b2d, const float* __restrict__ tpw,
    const float* __restrict__ qpack, const u16* __restrict__ kpackb, const u16* __restrict__ bias2d,
    u32* __restrict__ attn32)
{
  const int i = blockIdx.x;
  const int lane = threadIdx.x & 63, wave = threadIdx.x >> 6;
  const float mi = mask[i];
  #pragma unroll
  for (int hh = 0; hh < 3; ++hh) {
    const int h = wave + 4*hh;
    f32x2 q2[14];
    #pragma unroll
    for (int c = 0; c < 14; ++c) {
      q2[c].x = qpack[(size_t)i*336 + h*28 + 2*c];
      q2[c].y = qpack[(size_t)i*336 + h*28 + 2*c + 1];
    }
    const float pw_c = 0.1360827635f * log1pf(expf(tpw[h]));
    const float b2_c = b2d[h];
    float lgt[12];
    for (int k2 = 0; k2 < 6; ++k2) {
      #pragma unroll
      for (int jj = 0; jj < 2; ++jj) {
        int j = k2*128 + 2*lane + jj;
        const uint4* kr = (const uint4*)(kpackb + ((size_t)j*12 + h)*32);
        uint4 ka = kr[0], kb = kr[1], kc2 = kr[2];
        uint2 kd = ((const uint2*)kr)[6];
        float bs = bflo((u32)bias2d[((size_t)i*NN + j)*12 + h]);
        float mj = mask[j];
        f32x2 qk2 = q2[0]*bfp(ka.x);
        qk2 += q2[1]*bfp(ka.y); qk2 += q2[2]*bfp(ka.z); qk2 += q2[3]*bfp(ka.w);
        qk2 += q2[4]*bfp(kb.x); qk2 += q2[5]*bfp(kb.y); qk2 += q2[6]*bfp(kb.z); qk2 += q2[7]*bfp(kb.w);
        f32x2 d, pt2;
        d = q2[8]  - bfp(kc2.x); pt2  = d*d;
        d = q2[9]  - bfp(kc2.y); pt2 += d*d;
        d = q2[10] - bfp(kc2.z); pt2 += d*d;
        d = q2[11] - bfp(kc2.w); pt2 += d*d;
        d = q2[12] - bfp(kd.x);  pt2 += d*d;
        d = q2[13] - bfp(kd.y);  pt2 += d*d;
        lgt[2*k2+jj] = 0.1443375673f*(qk2.x+qk2.y) - 0.5f*pw_c*(pt2.x+pt2.y)
                     + 0.5773502692f*(bs + b2_c) - 1e9f*(1.f - mi*mj);
      }
    }
    float m = lgt[0];
    #pragma unroll
    for (int k = 1; k < 12; ++k) m = fmaxf(m, lgt[k]);
    #pragma unroll
    for (int off = 32; off; off >>= 1) m = fmaxf(m, __shfl_xor(m, off));
    float s = 0.f;
    #pragma unroll
    for (int k = 0; k < 12; ++k) { lgt[k] = __expf(lgt[k]-m); s += lgt[k]; }
    #pragma unroll
    for (int off = 32; off; off >>= 1) s += __shfl_xor(s, off);
    float inv = 1.f / s;
    #pragma unroll
    for (int k2 = 0; k2 < 6; ++k2) {
      u32 lo = f2b(lgt[2*k2]*inv), hi = f2b(lgt[2*k2+1]*inv);
      attn32[((size_t)i*12 + h)*384 + k2*64 + lane] = lo | (hi << 16);
    }
  }
}

// ---------------- K4 (v2): o2d = attn @ in2d — barrier-free, LDS-free, wave-per-(i,c16) ----------------
// 6144 waves; wave gw -> i = 767 - (gw>>3) (descending i: rides k_bias2d's L3 tail),
// c-block = (gw&7)*16. D[16h,16c] = P[16h,768j] @ in2d[i,:,c16] as 24 MFMAs.
// A (P) direct 16B loads from attn row; B direct scalar f32 loads + cvt (lanes:
// 16 consecutive c x 4 j-rows = coalesced 64B segments). Zero sync anywhere.
__global__ __launch_bounds__(256) void k_o2d(
    const float* __restrict__ in2d, const u16* __restrict__ attn16, float* __restrict__ fact)
{
  const int lane = threadIdx.x & 63;
  const int gw = blockIdx.x*4 + (threadIdx.x >> 6);
  const int i = 767 - (gw >> 3);
  const int cbase = (gw & 7) * 16;
  const int hcol = lane & 15, lg4 = lane >> 4;
  const int hq = (hcol < 12) ? hcol : 0;

  const u16*  prow = attn16 + ((size_t)i*12 + hq)*NN;
  const float* brow = in2d + (size_t)i*NN*128 + cbase + hcol;

  f32x4 acc = {0.f,0.f,0.f,0.f};
  for (int t = 0; t < 12; ++t) {
    #pragma unroll
    for (int ks = 0; ks < 2; ++ks) {
      const int jb = t*64 + ks*32 + lg4*8;
      bf16x8 pf = *(const bf16x8*)(prow + jb);
      bf16x8 bf;
      #pragma unroll
      for (int e = 0; e < 8; ++e)
        bf[e] = (short)f2b(brow[(size_t)(jb + e)*128]);
      acc = __builtin_amdgcn_mfma_f32_16x16x32_bf16(pf, bf, acc, 0, 0, 0);
    }
  }
  #pragma unroll
  for (int r = 0; r < 4; ++r) {
    int h = lg4*4 + r;
    if (h < 12)
      fact[(size_t)i*FACT + 576 + (size_t)h*128 + cbase + hcol] = acc[r];
  }
}

// ---------------- K5: attn @ [v_scalar | v_point] + inverse frame + norms (r8-proven) ----------------
__global__ __launch_bounds__(256) void k_av(
    const u16* __restrict__ attn16, const u16* __restrict__ vpackb,
    const float* __restrict__ rot, const float* __restrict__ trans,
    float* __restrict__ fact)
{
  const int i0 = blockIdx.x * 32;
  const int h = blockIdx.y;
  __shared__ float A[32*65];
  __shared__ float Vt[64*40];
  __shared__ float O[32*41];
  const int tid = threadIdx.x;
  const int r = tid >> 3, ug = tid & 7;
  float acc[5] = {0,0,0,0,0};
  for (int j0 = 0; j0 < NN; j0 += 64) {
    {
      uint4 u = *(const uint4*)(attn16 + ((size_t)(i0 + (tid>>3))*12 + h)*NN + j0 + (tid&7)*8);
      float* dst = &A[(tid>>3)*65 + (tid&7)*8];
      dst[0]=bflo(u.x); dst[1]=bfhi(u.x); dst[2]=bflo(u.y); dst[3]=bfhi(u.y);
      dst[4]=bflo(u.z); dst[5]=bfhi(u.z); dst[6]=bflo(u.w); dst[7]=bfhi(u.w);
    }
    for (int idx = tid; idx < 320; idx += 256) {
      int j = idx / 5, g = idx - j*5;
      uint4 u = *(const uint4*)(vpackb + ((size_t)h*NN + j0 + j)*40 + g*8);
      float* dst = &Vt[j*40 + g*8];
      dst[0]=bflo(u.x); dst[1]=bfhi(u.x); dst[2]=bflo(u.y); dst[3]=bfhi(u.y);
      dst[4]=bflo(u.z); dst[5]=bfhi(u.z); dst[6]=bflo(u.w); dst[7]=bfhi(u.w);
    }
    __syncthreads();
    #pragma unroll 8
    for (int jj = 0; jj < 64; ++jj) {
      float a = A[r*65 + jj];
      #pragma unroll
      for (int k = 0; k < 5; ++k) acc[k] += a * Vt[jj*40 + ug*5 + k];
    }
    __syncthreads();
  }
  #pragma unroll
  for (int k = 0; k < 5; ++k) O[r*41 + ug*5 + k] = acc[k];
  __syncthreads();
  for (int idx = tid; idx < 32*16; idx += 256) {
    int rr = idx >> 4, c = idx & 15;
    fact[(size_t)(i0+rr)*FACT + h*16 + c] = O[rr*41 + c];
  }
  {
    int rr = tid >> 3, p = tid & 7;
    int n = i0 + rr;
    float g0 = O[rr*41 + 16 + p*3 + 0] - trans[n*3+0];
    float g1 = O[rr*41 + 16 + p*3 + 1] - trans[n*3+1];
    float g2 = O[rr*41 + 16 + p*3 + 2] - trans[n*3+2];
    const float* R = rot + n*9;
    float l0 = R[0]*g0 + R[3]*g1 + R[6]*g2;
    float l1 = R[1]*g0 + R[4]*g1 + R[7]*g2;
    float l2 = R[2]*g0 + R[5]*g1 + R[8]*g2;
    float* fr = fact + (size_t)n*FACT;
    fr[192 +   0 + h*8 + p] = l0;
    fr[192 +  96 + h*8 + p] = l1;
    fr[192 + 192 + h*8 + p] = l2;
    fr[480 + h*8 + p] = sqrtf(1e-8f + l0*l0 + l1*l1 + l2*l2);
  }
}

// ---------------- K6: final_act @ wout (K-split partials, r8-proven) ----------------
__global__ __launch_bounds__(256) void k_out_part(
    const float* __restrict__ fact, const float* __restrict__ wout, float* __restrict__ pout)
{
  const int r0 = blockIdx.x * 32;
  const int c0 = blockIdx.y * 64;
  const int kc = blockIdx.z;
  __shared__ float xs[32][64];
  const int tid = threadIdx.x;
  const int co = tid & 63, rg = tid >> 6;
  float acc[8] = {0.f,0.f,0.f,0.f,0.f,0.f,0.f,0.f};
  for (int ks = 0; ks < 11; ++ks) {
    int k0 = kc*704 + ks*64;
    for (int idx = tid; idx < 2048; idx += 256) {
      int rr = idx >> 6, kx = idx & 63;
      xs[rr][kx] = fact[(size_t)(r0+rr)*FACT + k0 + kx];
    }
    __syncthreads();
    for (int kk = 0; kk < 64; ++kk) {
      float w = wout[(size_t)(k0+kk)*384 + c0 + co];
      #pragma unroll
      for (int rr = 0; rr < 8; ++rr) acc[rr] += xs[rg*8+rr][kk]*w;
    }
    __syncthreads();
  }
  #pragma unroll
  for (int rr = 0; rr < 8; ++rr)
    pout[((size_t)kc*NN + r0 + rg*8 + rr)*384 + c0 + co] = acc[rr];
}

__global__ __launch_bounds__(256) void k_out_red(
    const float* __restrict__ pout, const float* __restrict__ bout, float* __restrict__ out)
{
  int idx = blockIdx.x*256 + threadIdx.x;
  out[idx] = bout[idx % 384] + pout[idx] + pout[294912 + idx] + pout[2*294912 + idx];
}

extern "C" void kernel_launch(void* const* d_in, const int* in_sizes, int n_in,
                              void* d_out, int out_size, void* d_ws, size_t ws_size,
                              hipStream_t stream) {
  const float* in1d  = (const float*)d_in[0];
  const float* in2d  = (const float*)d_in[1];
  const float* mask  = (const float*)d_in[2];
  const float* rot   = (const float*)d_in[3];
  const float* trans = (const float*)d_in[4];
  const float* wq    = (const float*)d_in[5];
  const float* bq    = (const float*)d_in[6];
  const float* wkv   = (const float*)d_in[7];
  const float* bkv   = (const float*)d_in[8];
  const float* wqp   = (const float*)d_in[9];
  const float* bqp   = (const float*)d_in[10];
  const float* wkvp  = (const float*)d_in[11];
  const float* bkvp  = (const float*)d_in[12];
  const float* w2d   = (const float*)d_in[13];
  const float* b2d   = (const float*)d_in[14];
  const float* tpw   = (const float*)d_in[15];
  const float* wout  = (const float*)d_in[16];
  const float* bout  = (const float*)d_in[17];

  float* ws = (float*)d_ws;
  float* qpack   = ws;                        // 258048
  u16*   kpackb  = (u16*)(ws + 258048);       // 294912 bf16 (147456 slots)
  u16*   vpackb  = (u16*)(ws + 405504);       // 368640 bf16 (184320 slots)
  u16*   attn16  = (u16*)(ws + 589824);       // 7077888 bf16 -> ends 4128768
  u16*   bias2d  = (u16*)(ws + 4128768);      // 7077888 bf16 -> ends 7667712
  float* fact    = ws + 4128768;              // aliases bias2d (dead after k_attn)
  float* pout    = ws + 5750784;              // ends 6635520 <= 7667712
  float* out     = (float*)d_out;

  k_proj   <<<dim3(96,4), 256, 0, stream>>>(in1d, rot, trans, wq, bq, wkv, bkv, wqp, bqp,
                                            wkvp, bkvp, qpack, kpackb, vpackb);
  k_bias2d <<<1024, 256, 0, stream>>>(in2d, w2d, bias2d);
  k_attn   <<<768, 256, 0, stream>>>(mask, b2d, tpw, qpack, kpackb, bias2d, (u32*)attn16);
  k_o2d    <<<1536, 256, 0, stream>>>(in2d, attn16, fact);
  k_av     <<<dim3(24,12), 256, 0, stream>>>(attn16, vpackb, rot, trans, fact);
  k_out_part<<<dim3(24,6,3), 256, 0, stream>>>(fact, wout, pout);
  k_out_red <<<1152, 256, 0, stream>>>(pout, bout, out);
}

// Round 11
// 422.452 us; speedup vs baseline: 1.0599x; 1.0599x over previous
//
#include <hip/hip_runtime.h>
#include <hip/hip_bf16.h>

#define NN 768
#define CM 384
#define FACT 2112

typedef __attribute__((ext_vector_type(8))) short bf16x8;
typedef __attribute__((ext_vector_type(4))) short bf16x4;
typedef __attribute__((ext_vector_type(4))) float f32x4;
typedef __attribute__((ext_vector_type(2))) float f32x2;
typedef unsigned int u32;
typedef unsigned short u16;

__device__ __forceinline__ float bflo(u32 u){ union{u32 i; float f;} x; x.i = u << 16; return x.f; }
__device__ __forceinline__ float bfhi(u32 u){ union{u32 i; float f;} x; x.i = u & 0xffff0000u; return x.f; }
__device__ __forceinline__ f32x2 bfp(u32 u){
  union { u32 i[2]; f32x2 v; } x;
  x.i[0] = u << 16; x.i[1] = u & 0xffff0000u;
  return x.v;
}
__device__ __forceinline__ u16 f2b(float f){ __hip_bfloat16 b = __float2bfloat16(f); return *(u16*)&b; }

// ---------------- K1: projections + frame rotation (r8 version — r9 "v2" regressed 26us, reverted) ----------------
__global__ __launch_bounds__(256) void k_proj(
    const float* __restrict__ in1d, const float* __restrict__ rot, const float* __restrict__ trans,
    const float* __restrict__ wq, const float* __restrict__ bq,
    const float* __restrict__ wkv, const float* __restrict__ bkv,
    const float* __restrict__ wqp, const float* __restrict__ bqp,
    const float* __restrict__ wkvp, const float* __restrict__ bkvp,
    float* __restrict__ qpack, u16* __restrict__ kpackb, u16* __restrict__ vpackb)
{
  const int n0 = blockIdx.x * 2;
  const int tid = threadIdx.x;
  __shared__ float x[2][CM];
  __shared__ float rs[2][9], ts[2][3];
  for (int idx = tid; idx < 2*CM; idx += 256)
    x[idx/CM][idx%CM] = in1d[(size_t)(n0 + idx/CM)*CM + idx%CM];
  if (tid < 18) rs[tid/9][tid%9] = rot[n0*9 + tid];
  if (tid < 6)  ts[tid/3][tid%3] = trans[n0*3 + tid];
  __syncthreads();
  for (int it = tid; it < 2*576; it += 256) {
    int r = it / 576, o = it % 576;
    const float* xr = x[r]; int n = n0 + r;
    if (o < 192) {
      float acc = bq[o];
      for (int c4 = 0; c4 < 96; ++c4) {
        float4 xv = *(const float4*)(xr + c4*4);
        const float* wp = wq + (size_t)c4*4*192 + o;
        acc += xv.x*wp[0] + xv.y*wp[192] + xv.z*wp[384] + xv.w*wp[576];
      }
      qpack[((size_t)n*12 + (o>>4))*28 + (o&15)] = acc;
    } else {
      int o2 = o - 192;
      float acc = bkv[o2];
      for (int c4 = 0; c4 < 96; ++c4) {
        float4 xv = *(const float4*)(xr + c4*4);
        const float* wp = wkv + (size_t)c4*4*384 + o2;
        acc += xv.x*wp[0] + xv.y*wp[384] + xv.z*wp[768] + xv.w*wp[1152];
      }
      int h = o2 >> 5, u = o2 & 31;
      if (u < 16) kpackb[((size_t)n*12 + h)*32 + u] = f2b(acc);
      else        vpackb[((size_t)h*NN + n)*40 + (u - 16)] = f2b(acc);
    }
  }
  for (int it = tid; it < 2*192; it += 256) {
    int r = it / 192, ch = it % 192;
    const float* xr = x[r];
    float l0, l1, l2; int h, u; bool isq;
    if (ch < 48) {
      l0 = bqp[ch]; l1 = bqp[48+ch]; l2 = bqp[96+ch];
      for (int c4 = 0; c4 < 96; ++c4) {
        float4 xv = *(const float4*)(xr + c4*4);
        const float* wp = wqp + (size_t)c4*4*144 + ch;
        l0 += xv.x*wp[0]  + xv.y*wp[144] + xv.z*wp[288] + xv.w*wp[432];
        l1 += xv.x*wp[48] + xv.y*wp[192] + xv.z*wp[336] + xv.w*wp[480];
        l2 += xv.x*wp[96] + xv.y*wp[240] + xv.z*wp[384] + xv.w*wp[528];
      }
      h = ch >> 2; u = ch & 3; isq = true;
    } else {
      int c2 = ch - 48;
      l0 = bkvp[c2]; l1 = bkvp[144+c2]; l2 = bkvp[288+c2];
      for (int c4 = 0; c4 < 96; ++c4) {
        float4 xv = *(const float4*)(xr + c4*4);
        const float* wp = wkvp + (size_t)c4*4*432 + c2;
        l0 += xv.x*wp[0]   + xv.y*wp[432] + xv.z*wp[864]  + xv.w*wp[1296];
        l1 += xv.x*wp[144] + xv.y*wp[576] + xv.z*wp[1008] + xv.w*wp[1440];
        l2 += xv.x*wp[288] + xv.y*wp[720] + xv.z*wp[1152] + xv.w*wp[1584];
      }
      h = c2 / 12; u = c2 % 12; isq = false;
    }
    float g0 = rs[r][0]*l0 + rs[r][1]*l1 + rs[r][2]*l2 + ts[r][0];
    float g1 = rs[r][3]*l0 + rs[r][4]*l1 + rs[r][5]*l2 + ts[r][1];
    float g2 = rs[r][6]*l0 + rs[r][7]*l1 + rs[r][8]*l2 + ts[r][2];
    int n = n0 + r;
    if (isq) {
      float* p = &qpack[((size_t)n*12 + h)*28 + 16 + u*3];
      p[0]=g0; p[1]=g1; p[2]=g2;
    } else if (u < 4) {
      u16* p = &kpackb[((size_t)n*12 + h)*32 + 16 + u*3];
      p[0]=f2b(g0); p[1]=f2b(g1); p[2]=f2b(g2);
    } else {
      u16* p = &vpackb[((size_t)h*NN + n)*40 + 16 + (u-4)*3];
      p[0]=f2b(g0); p[1]=f2b(g1); p[2]=f2b(g2);
    }
  }
}

// ---------------- K2 (v3): bias2d = in2d @ w2d — coalesced via per-wave-PRIVATE LDS staging ----------------
// The 16x128 f32 A-tile is CONTIGUOUS memory. Stage as a flat 8KB copy
// (8 fully-coalesced 1KB dwordx4 loads), cvt to bf16 into a wave-private
// swizzled LDS tile, then ds_read_b128 A-frags. No barriers — same-wave LDS
// producer/consumer ordered by compiler-inserted lgkmcnt waits. Replaces the
// r8-r10 direct loads whose instructions touched 64 scattered 16B segments.
__global__ __launch_bounds__(256) void k_bias2d(
    const float* __restrict__ in2d, const float* __restrict__ w2d, u16* __restrict__ bias2d)
{
  const int lane = threadIdx.x & 63, wave = threadIdx.x >> 6;
  const int hcol = lane & 15, lg4 = lane >> 4;
  __shared__ __align__(16) u16 stg[4][16*128];
  u16* S = stg[wave];

  bf16x8 wfrag[4];
  #pragma unroll
  for (int kk = 0; kk < 4; ++kk)
    #pragma unroll
    for (int e = 0; e < 8; ++e) {
      int c = kk*32 + lg4*8 + e;
      wfrag[kk][e] = (short)((hcol < 12) ? f2b(w2d[c*12 + hcol]) : (u16)0);
    }

  const int gw = blockIdx.x*4 + wave;
  const int wrow = lane >> 5;          // 0..1
  const int wcb  = (lane & 31) * 8;    // byte col within row
  for (int tile = gw; tile < 36864; tile += 4096) {
    const size_t m0 = (size_t)tile * 16;
    const float* src = in2d + m0*128;
    #pragma unroll
    for (int k = 0; k < 8; ++k) {
      float4 v = *(const float4*)(src + (size_t)lane*4 + k*256);   // 1KB contiguous/inst
      int row = wrow + k*2;
      bf16x4 pk;
      pk[0]=(short)f2b(v.x); pk[1]=(short)f2b(v.y);
      pk[2]=(short)f2b(v.z); pk[3]=(short)f2b(v.w);
      *(bf16x4*)((char*)S + row*256 + (wcb ^ ((row&7)<<4))) = pk;
    }
    f32x4 acc = {0.f,0.f,0.f,0.f};
    #pragma unroll
    for (int kk = 0; kk < 4; ++kk) {
      bf16x8 a = *(const bf16x8*)((char*)S + hcol*256 + (((kk*32 + lg4*8)*2) ^ ((hcol&7)<<4)));
      acc = __builtin_amdgcn_mfma_f32_16x16x32_bf16(a, wfrag[kk], acc, 0, 0, 0);
    }
    if (hcol < 12) {
      #pragma unroll
      for (int r = 0; r < 4; ++r)
        bias2d[(m0 + lg4*4 + r)*12 + hcol] = f2b(acc[r]);
    }
  }
}

// ---------------- K3: logits + softmax -> normalized attn bf16 [i][h][j] (r8-proven) ----------------
__global__ __launch_bounds__(256) void k_attn(
    const float* __restrict__ mask, const float* __restrict__ b2d, const float* __restrict__ tpw,
    const float* __restrict__ qpack, const u16* __restrict__ kpackb, const u16* __restrict__ bias2d,
    u32* __restrict__ attn32)
{
  const int i = blockIdx.x;
  const int lane = threadIdx.x & 63, wave = threadIdx.x >> 6;
  const float mi = mask[i];
  #pragma unroll
  for (int hh = 0; hh < 3; ++hh) {
    const int h = wave + 4*hh;
    f32x2 q2[14];
    #pragma unroll
    for (int c = 0; c < 14; ++c) {
      q2[c].x = qpack[(size_t)i*336 + h*28 + 2*c];
      q2[c].y = qpack[(size_t)i*336 + h*28 + 2*c + 1];
    }
    const float pw_c = 0.1360827635f * log1pf(expf(tpw[h]));
    const float b2_c = b2d[h];
    float lgt[12];
    for (int k2 = 0; k2 < 6; ++k2) {
      #pragma unroll
      for (int jj = 0; jj < 2; ++jj) {
        int j = k2*128 + 2*lane + jj;
        const uint4* kr = (const uint4*)(kpackb + ((size_t)j*12 + h)*32);
        uint4 ka = kr[0], kb = kr[1], kc2 = kr[2];
        uint2 kd = ((const uint2*)kr)[6];
        float bs = bflo((u32)bias2d[((size_t)i*NN + j)*12 + h]);
        float mj = mask[j];
        f32x2 qk2 = q2[0]*bfp(ka.x);
        qk2 += q2[1]*bfp(ka.y); qk2 += q2[2]*bfp(ka.z); qk2 += q2[3]*bfp(ka.w);
        qk2 += q2[4]*bfp(kb.x); qk2 += q2[5]*bfp(kb.y); qk2 += q2[6]*bfp(kb.z); qk2 += q2[7]*bfp(kb.w);
        f32x2 d, pt2;
        d = q2[8]  - bfp(kc2.x); pt2  = d*d;
        d = q2[9]  - bfp(kc2.y); pt2 += d*d;
        d = q2[10] - bfp(kc2.z); pt2 += d*d;
        d = q2[11] - bfp(kc2.w); pt2 += d*d;
        d = q2[12] - bfp(kd.x);  pt2 += d*d;
        d = q2[13] - bfp(kd.y);  pt2 += d*d;
        lgt[2*k2+jj] = 0.1443375673f*(qk2.x+qk2.y) - 0.5f*pw_c*(pt2.x+pt2.y)
                     + 0.5773502692f*(bs + b2_c) - 1e9f*(1.f - mi*mj);
      }
    }
    float m = lgt[0];
    #pragma unroll
    for (int k = 1; k < 12; ++k) m = fmaxf(m, lgt[k]);
    #pragma unroll
    for (int off = 32; off; off >>= 1) m = fmaxf(m, __shfl_xor(m, off));
    float s = 0.f;
    #pragma unroll
    for (int k = 0; k < 12; ++k) { lgt[k] = __expf(lgt[k]-m); s += lgt[k]; }
    #pragma unroll
    for (int off = 32; off; off >>= 1) s += __shfl_xor(s, off);
    float inv = 1.f / s;
    #pragma unroll
    for (int k2 = 0; k2 < 6; ++k2) {
      u32 lo = f2b(lgt[2*k2]*inv), hi = f2b(lgt[2*k2+1]*inv);
      attn32[((size_t)i*12 + h)*384 + k2*64 + lane] = lo | (hi << 16);
    }
  }
}

// ---------------- K4: o2d = attn @ in2d — barrier-free, LDS-free (r10) ----------------
__global__ __launch_bounds__(256) void k_o2d(
    const float* __restrict__ in2d, const u16* __restrict__ attn16, float* __restrict__ fact)
{
  const int lane = threadIdx.x & 63;
  const int gw = blockIdx.x*4 + (threadIdx.x >> 6);
  const int i = 767 - (gw >> 3);
  const int cbase = (gw & 7) * 16;
  const int hcol = lane & 15, lg4 = lane >> 4;
  const int hq = (hcol < 12) ? hcol : 0;

  const u16*  prow = attn16 + ((size_t)i*12 + hq)*NN;
  const float* brow = in2d + (size_t)i*NN*128 + cbase + hcol;

  f32x4 acc = {0.f,0.f,0.f,0.f};
  for (int t = 0; t < 12; ++t) {
    #pragma unroll
    for (int ks = 0; ks < 2; ++ks) {
      const int jb = t*64 + ks*32 + lg4*8;
      bf16x8 pf = *(const bf16x8*)(prow + jb);
      bf16x8 bf;
      #pragma unroll
      for (int e = 0; e < 8; ++e)
        bf[e] = (short)f2b(brow[(size_t)(jb + e)*128]);
      acc = __builtin_amdgcn_mfma_f32_16x16x32_bf16(pf, bf, acc, 0, 0, 0);
    }
  }
  #pragma unroll
  for (int r = 0; r < 4; ++r) {
    int h = lg4*4 + r;
    if (h < 12)
      fact[(size_t)i*FACT + 576 + (size_t)h*128 + cbase + hcol] = acc[r];
  }
}

// ---------------- K5: attn @ [v_scalar | v_point] + inverse frame + norms (r8-proven) ----------------
__global__ __launch_bounds__(256) void k_av(
    const u16* __restrict__ attn16, const u16* __restrict__ vpackb,
    const float* __restrict__ rot, const float* __restrict__ trans,
    float* __restrict__ fact)
{
  const int i0 = blockIdx.x * 32;
  const int h = blockIdx.y;
  __shared__ float A[32*65];
  __shared__ float Vt[64*40];
  __shared__ float O[32*41];
  const int tid = threadIdx.x;
  const int r = tid >> 3, ug = tid & 7;
  float acc[5] = {0,0,0,0,0};
  for (int j0 = 0; j0 < NN; j0 += 64) {
    {
      uint4 u = *(const uint4*)(attn16 + ((size_t)(i0 + (tid>>3))*12 + h)*NN + j0 + (tid&7)*8);
      float* dst = &A[(tid>>3)*65 + (tid&7)*8];
      dst[0]=bflo(u.x); dst[1]=bfhi(u.x); dst[2]=bflo(u.y); dst[3]=bfhi(u.y);
      dst[4]=bflo(u.z); dst[5]=bfhi(u.z); dst[6]=bflo(u.w); dst[7]=bfhi(u.w);
    }
    for (int idx = tid; idx < 320; idx += 256) {
      int j = idx / 5, g = idx - j*5;
      uint4 u = *(const uint4*)(vpackb + ((size_t)h*NN + j0 + j)*40 + g*8);
      float* dst = &Vt[j*40 + g*8];
      dst[0]=bflo(u.x); dst[1]=bfhi(u.x); dst[2]=bflo(u.y); dst[3]=bfhi(u.y);
      dst[4]=bflo(u.z); dst[5]=bfhi(u.z); dst[6]=bflo(u.w); dst[7]=bfhi(u.w);
    }
    __syncthreads();
    #pragma unroll 8
    for (int jj = 0; jj < 64; ++jj) {
      float a = A[r*65 + jj];
      #pragma unroll
      for (int k = 0; k < 5; ++k) acc[k] += a * Vt[jj*40 + ug*5 + k];
    }
    __syncthreads();
  }
  #pragma unroll
  for (int k = 0; k < 5; ++k) O[r*41 + ug*5 + k] = acc[k];
  __syncthreads();
  for (int idx = tid; idx < 32*16; idx += 256) {
    int rr = idx >> 4, c = idx & 15;
    fact[(size_t)(i0+rr)*FACT + h*16 + c] = O[rr*41 + c];
  }
  {
    int rr = tid >> 3, p = tid & 7;
    int n = i0 + rr;
    float g0 = O[rr*41 + 16 + p*3 + 0] - trans[n*3+0];
    float g1 = O[rr*41 + 16 + p*3 + 1] - trans[n*3+1];
    float g2 = O[rr*41 + 16 + p*3 + 2] - trans[n*3+2];
    const float* R = rot + n*9;
    float l0 = R[0]*g0 + R[3]*g1 + R[6]*g2;
    float l1 = R[1]*g0 + R[4]*g1 + R[7]*g2;
    float l2 = R[2]*g0 + R[5]*g1 + R[8]*g2;
    float* fr = fact + (size_t)n*FACT;
    fr[192 +   0 + h*8 + p] = l0;
    fr[192 +  96 + h*8 + p] = l1;
    fr[192 + 192 + h*8 + p] = l2;
    fr[480 + h*8 + p] = sqrtf(1e-8f + l0*l0 + l1*l1 + l2*l2);
  }
}

// ---------------- K6: final_act @ wout (K-split partials, r8-proven) ----------------
__global__ __launch_bounds__(256) void k_out_part(
    const float* __restrict__ fact, const float* __restrict__ wout, float* __restrict__ pout)
{
  const int r0 = blockIdx.x * 32;
  const int c0 = blockIdx.y * 64;
  const int kc = blockIdx.z;
  __shared__ float xs[32][64];
  const int tid = threadIdx.x;
  const int co = tid & 63, rg = tid >> 6;
  float acc[8] = {0.f,0.f,0.f,0.f,0.f,0.f,0.f,0.f};
  for (int ks = 0; ks < 11; ++ks) {
    int k0 = kc*704 + ks*64;
    for (int idx = tid; idx < 2048; idx += 256) {
      int rr = idx >> 6, kx = idx & 63;
      xs[rr][kx] = fact[(size_t)(r0+rr)*FACT + k0 + kx];
    }
    __syncthreads();
    for (int kk = 0; kk < 64; ++kk) {
      float w = wout[(size_t)(k0+kk)*384 + c0 + co];
      #pragma unroll
      for (int rr = 0; rr < 8; ++rr) acc[rr] += xs[rg*8+rr][kk]*w;
    }
    __syncthreads();
  }
  #pragma unroll
  for (int rr = 0; rr < 8; ++rr)
    pout[((size_t)kc*NN + r0 + rg*8 + rr)*384 + c0 + co] = acc[rr];
}

__global__ __launch_bounds__(256) void k_out_red(
    const float* __restrict__ pout, const float* __restrict__ bout, float* __restrict__ out)
{
  int idx = blockIdx.x*256 + threadIdx.x;
  out[idx] = bout[idx % 384] + pout[idx] + pout[294912 + idx] + pout[2*294912 + idx];
}

extern "C" void kernel_launch(void* const* d_in, const int* in_sizes, int n_in,
                              void* d_out, int out_size, void* d_ws, size_t ws_size,
                              hipStream_t stream) {
  const float* in1d  = (const float*)d_in[0];
  const float* in2d  = (const float*)d_in[1];
  const float* mask  = (const float*)d_in[2];
  const float* rot   = (const float*)d_in[3];
  const float* trans = (const float*)d_in[4];
  const float* wq    = (const float*)d_in[5];
  const float* bq    = (const float*)d_in[6];
  const float* wkv   = (const float*)d_in[7];
  const float* bkv   = (const float*)d_in[8];
  const float* wqp   = (const float*)d_in[9];
  const float* bqp   = (const float*)d_in[10];
  const float* wkvp  = (const float*)d_in[11];
  const float* bkvp  = (const float*)d_in[12];
  const float* w2d   = (const float*)d_in[13];
  const float* b2d   = (const float*)d_in[14];
  const float* tpw   = (const float*)d_in[15];
  const float* wout  = (const float*)d_in[16];
  const float* bout  = (const float*)d_in[17];

  float* ws = (float*)d_ws;
  float* qpack   = ws;                        // 258048
  u16*   kpackb  = (u16*)(ws + 258048);       // 294912 bf16 (147456 slots)
  u16*   vpackb  = (u16*)(ws + 405504);       // 368640 bf16 (184320 slots)
  u16*   attn16  = (u16*)(ws + 589824);       // 7077888 bf16 -> ends 4128768
  u16*   bias2d  = (u16*)(ws + 4128768);      // 7077888 bf16 -> ends 7667712
  float* fact    = ws + 4128768;              // aliases bias2d (dead after k_attn)
  float* pout    = ws + 5750784;              // ends 6635520 <= 7667712
  float* out     = (float*)d_out;

  k_proj   <<<384, 256, 0, stream>>>(in1d, rot, trans, wq, bq, wkv, bkv, wqp, bqp,
                                     wkvp, bkvp, qpack, kpackb, vpackb);
  k_bias2d <<<1024, 256, 0, stream>>>(in2d, w2d, bias2d);
  k_attn   <<<768, 256, 0, stream>>>(mask, b2d, tpw, qpack, kpackb, bias2d, (u32*)attn16);
  k_o2d    <<<1536, 256, 0, stream>>>(in2d, attn16, fact);
  k_av     <<<dim3(24,12), 256, 0, stream>>>(attn16, vpackb, rot, trans, fact);
  k_out_part<<<dim3(24,6,3), 256, 0, stream>>>(fact, wout, pout);
  k_out_red <<<1152, 256, 0, stream>>>(pout, bout, out);
}